// Round 6
// baseline (348.564 us; speedup 1.0000x reference)
//
#include <hip/hip_runtime.h>
#include <math.h>

#define TT 4096
#define BB 32
#define DD 128
#define HH 256
#define KL 64
#define DM 1024
#define KEFF 64
#define KBUDGET 16.0f
#define LAM_ 0.5f

// fast tanh: 1 - 2/(1+exp2(x*2*log2e)); hw v_exp_f32 + v_rcp_f32 (~6 insts).
__device__ __forceinline__ float fast_tanh(float x) {
#if __has_builtin(__builtin_amdgcn_exp2f)
  float e = __builtin_amdgcn_exp2f(x * 2.885390081777927f);
#else
  float e = __expf(2.0f * x);
#endif
  float r = __builtin_amdgcn_rcpf(e + 1.0f);
  return fmaf(-2.0f, r, 1.0f);
}

// ---------------------------------------------------------------------------
// Kernel 1: saliency[b,t] = softplus( tanh(x@W1 + b1) @ w_s )
// 64 rows/block, 256 threads. x staged ONCE in LDS; W1 streamed from L2 with
// MANUAL double-buffered register prefetch (wA/wB, loads issued one FMA-block
// ahead -> ~220cy L2 latency hidden under 512 FMA-issue cycles).
// Wave = 8 row-groups x 8 h-groups; lane tile 8 rows x 8 h (acc[8][8]).
// ---------------------------------------------------------------------------
__global__ __launch_bounds__(256, 3) void k_sal(const float* __restrict__ x,
    const float* __restrict__ W1, const float* __restrict__ b1,
    const float* __restrict__ w_s, float* __restrict__ sal_out)
{
  __shared__ float xs[64][132];     // 33792 B; row stride 132 -> rq rows hit
                                    // distinct bank quads on b128 reads
  __shared__ float redsm[4][64];

  const int tid  = threadIdx.x;
  const int lane = tid & 63;
  const int wave = tid >> 6;
  const int rq = lane & 7;          // row group: rows rq + 8i
  const int hq = lane >> 3;         // 0..7, 8 h each
  const int h0 = wave * 64 + hq * 8;
  const long rowbase = (long)blockIdx.x * 64;

  // stage x tile: 64 rows x 128 d (2048 float4, coalesced)
  #pragma unroll
  for (int p = 0; p < 8; ++p) {
    int i = tid + p * 256;
    int r = i >> 5, c4 = i & 31;
    float4 v = *(const float4*)&x[(rowbase + r) * DD + c4 * 4];
    *(float4*)&xs[r][c4 * 4] = v;
  }
  __syncthreads();

  float acc[8][8];
  #pragma unroll
  for (int i = 0; i < 8; ++i)
    #pragma unroll
    for (int j = 0; j < 8; ++j) acc[i][j] = 0.f;

  const float* __restrict__ Wb = W1 + h0;

#define LOADW(BUF, D4)                                        \
  {                                                           \
    const float* wp = Wb + (size_t)(D4) * 4 * HH;             \
    BUF[0] = *(const float4*)&wp[0];                          \
    BUF[1] = *(const float4*)&wp[4];                          \
    BUF[2] = *(const float4*)&wp[HH];                         \
    BUF[3] = *(const float4*)&wp[HH + 4];                     \
    BUF[4] = *(const float4*)&wp[2 * HH];                     \
    BUF[5] = *(const float4*)&wp[2 * HH + 4];                 \
    BUF[6] = *(const float4*)&wp[3 * HH];                     \
    BUF[7] = *(const float4*)&wp[3 * HH + 4];                 \
  }

#define FMAROW(I, XD, WA, WB)                      \
  acc[I][0] = fmaf(XD, WA.x, acc[I][0]);           \
  acc[I][1] = fmaf(XD, WA.y, acc[I][1]);           \
  acc[I][2] = fmaf(XD, WA.z, acc[I][2]);           \
  acc[I][3] = fmaf(XD, WA.w, acc[I][3]);           \
  acc[I][4] = fmaf(XD, WB.x, acc[I][4]);           \
  acc[I][5] = fmaf(XD, WB.y, acc[I][5]);           \
  acc[I][6] = fmaf(XD, WB.z, acc[I][6]);           \
  acc[I][7] = fmaf(XD, WB.w, acc[I][7]);
#define FMAD(C, WA, WB)                            \
  FMAROW(0, xv0.C, WA, WB)                         \
  FMAROW(1, xv1.C, WA, WB)                         \
  FMAROW(2, xv2.C, WA, WB)                         \
  FMAROW(3, xv3.C, WA, WB)                         \
  FMAROW(4, xv4.C, WA, WB)                         \
  FMAROW(5, xv5.C, WA, WB)                         \
  FMAROW(6, xv6.C, WA, WB)                         \
  FMAROW(7, xv7.C, WA, WB)

#define FMABLOCK(D4, W)                                       \
  {                                                           \
    float4 xv0 = *(const float4*)&xs[rq +  0][(D4) * 4];      \
    float4 xv1 = *(const float4*)&xs[rq +  8][(D4) * 4];      \
    float4 xv2 = *(const float4*)&xs[rq + 16][(D4) * 4];      \
    float4 xv3 = *(const float4*)&xs[rq + 24][(D4) * 4];      \
    float4 xv4 = *(const float4*)&xs[rq + 32][(D4) * 4];      \
    float4 xv5 = *(const float4*)&xs[rq + 40][(D4) * 4];      \
    float4 xv6 = *(const float4*)&xs[rq + 48][(D4) * 4];      \
    float4 xv7 = *(const float4*)&xs[rq + 56][(D4) * 4];      \
    FMAD(x, W[0], W[1])                                       \
    FMAD(y, W[2], W[3])                                       \
    FMAD(z, W[4], W[5])                                       \
    FMAD(w, W[6], W[7])                                       \
  }

  float4 wA[8], wB[8];
  LOADW(wA, 0)
  #pragma unroll 1
  for (int d4 = 0; d4 < 30; d4 += 2) {
    LOADW(wB, d4 + 1)      // in flight while wA is consumed
    FMABLOCK(d4, wA)
    LOADW(wA, d4 + 2)      // in flight while wB is consumed
    FMABLOCK(d4 + 1, wB)
  }
  LOADW(wB, 31)
  FMABLOCK(30, wA)
  FMABLOCK(31, wB)

#undef FMABLOCK
#undef FMAD
#undef FMAROW
#undef LOADW

  // epilogue: tanh + w_s dot over this lane's 8 h columns
  float4 ba  = *(const float4*)&b1[h0];
  float4 bb  = *(const float4*)&b1[h0 + 4];
  float4 wsa = *(const float4*)&w_s[h0];
  float4 wsb = *(const float4*)&w_s[h0 + 4];
  float s_acc[8];
  #pragma unroll
  for (int i = 0; i < 8; ++i) {
    float s = 0.f;
    s = fmaf(fast_tanh(acc[i][0] + ba.x), wsa.x, s);
    s = fmaf(fast_tanh(acc[i][1] + ba.y), wsa.y, s);
    s = fmaf(fast_tanh(acc[i][2] + ba.z), wsa.z, s);
    s = fmaf(fast_tanh(acc[i][3] + ba.w), wsa.w, s);
    s = fmaf(fast_tanh(acc[i][4] + bb.x), wsb.x, s);
    s = fmaf(fast_tanh(acc[i][5] + bb.y), wsb.y, s);
    s = fmaf(fast_tanh(acc[i][6] + bb.z), wsb.z, s);
    s = fmaf(fast_tanh(acc[i][7] + bb.w), wsb.w, s);
    s_acc[i] = s;
  }
  // reduce across the 8 hq groups (masks 8,16,32)
  #pragma unroll
  for (int m = 8; m < 64; m <<= 1) {
    #pragma unroll
    for (int i = 0; i < 8; ++i) s_acc[i] += __shfl_xor(s_acc[i], m, 64);
  }
  if (hq == 0) {
    #pragma unroll
    for (int i = 0; i < 8; ++i) redsm[wave][rq + 8 * i] = s_acc[i];
  }
  __syncthreads();
  if (tid < 64) {
    float z = redsm[0][tid] + redsm[1][tid] + redsm[2][tid] + redsm[3][tid];
    float sp = fmaxf(z, 0.f) + log1pf(expf(-fabsf(z)));  // stable softplus
    sal_out[rowbase + tid] = sp;
  }
}

// ---------------------------------------------------------------------------
// Kernel 2: per-batch selector. y_star + cumsum + exact top-64
// (desc value, ties -> lower index). Top-64: each wave builds the exact
// sorted top-64 of its 1024-quarter (registers + bitmask, shuffle-only, NO
// barriers), then one thread 4-way-merges the sorted lists (64 steps).
// ---------------------------------------------------------------------------
__global__ __launch_bounds__(256) void k_sel(const float* __restrict__ logt,
    float* __restrict__ ysr, int* __restrict__ topidx,
    float* __restrict__ topsal, float* __restrict__ topcums)
{
  __shared__ float sal[TT];
  __shared__ float ya[TT];   // y (pre-refractory), then reused as cumsum
  __shared__ float yb[TT];   // y_star
  __shared__ float redf[8];
  __shared__ float wl_val[4][KEFF];
  __shared__ int   wl_idx[4][KEFF];

  const int tid = threadIdx.x;
  const int lane = tid & 63;
  const int wave = tid >> 6;
  const int b = blockIdx.x;
  float* row = ysr + (long)b * TT;

  for (int i = tid; i < TT; i += 256) sal[i] = row[i];
  __syncthreads();

  float temp = expf(logt[0]);
  temp = fminf(fmaxf(temp, 0.1f), 10.f);
  const float inv2lam = 1.0f / (2.0f * LAM_);

  for (int i = tid; i < TT; i += 256) {
    float z = (sal[i] * inv2lam - 0.5f) / temp;
    float s;
    if (z >= 0.f) { float e = expf(-z); s = 1.f / (1.f + e); }
    else          { float e = expf(z);  s = e / (1.f + e); }
    ya[i] = (i == 0) ? 0.f : s;
  }
  __syncthreads();

  float loc = 0.f;
  for (int i = tid; i < TT; i += 256) loc += ya[i];
  #pragma unroll
  for (int m = 1; m < 64; m <<= 1) loc += __shfl_xor(loc, m, 64);
  if (lane == 0) redf[wave] = loc;
  __syncthreads();
  float budget = redf[0] + redf[1] + redf[2] + redf[3];
  float scale = fminf(KBUDGET / fmaxf(budget, 1e-6f), 1.f);

  for (int i = tid; i < TT; i += 256) {
    float yi = ya[i] * scale;
    float yj = ya[(i + 1) & (TT - 1)] * scale;
    float m = fminf(2.f / (1.f + (yi + yj)), 1.f);
    yb[i] = (i == 0) ? 0.f : yi * m;
  }
  __syncthreads();

  for (int i = tid; i < TT; i += 256) row[i] = yb[i];   // y_star out

  // inclusive cumsum of saliency into ya
  const int base = tid * 16;
  float run = 0.f;
  #pragma unroll
  for (int j = 0; j < 16; ++j) { run += sal[base + j]; ya[base + j] = run; }
  float v = run;
  #pragma unroll
  for (int m = 1; m < 64; m <<= 1) {
    float u = __shfl_up(v, (unsigned)m, 64);
    if (lane >= m) v += u;
  }
  float lexcl = v - run;
  if (lane == 63) redf[4 + wave] = v;
  __syncthreads();
  float woff = 0.f;
  for (int w = 0; w < wave; ++w) woff += redf[4 + w];
  float off = woff + lexcl;
  #pragma unroll
  for (int j = 0; j < 16; ++j) ya[base + j] += off;
  __syncthreads();

  // per-wave exact sorted top-64 of its quarter (no barriers)
  const int qb = wave * 1024 + lane * 16;
  float lv[16];
  #pragma unroll
  for (int j = 0; j < 16; ++j) lv[j] = yb[qb + j];
  unsigned rm = 0;
  float bv = -1.f; int bi = 1 << 30;
  #pragma unroll
  for (int j = 0; j < 16; ++j)
    if (lv[j] > bv) { bv = lv[j]; bi = qb + j; }

  for (int it = 0; it < KEFF; ++it) {
    float cv = bv; int ci = bi;
    #pragma unroll
    for (int m = 1; m < 64; m <<= 1) {
      float ov = __shfl_xor(cv, m, 64);
      int   oi = __shfl_xor(ci, m, 64);
      if (ov > cv || (ov == cv && oi < ci)) { cv = ov; ci = oi; }
    }
    if (lane == 0) { wl_val[wave][it] = cv; wl_idx[wave][it] = ci; }
    if (ci >= qb && ci < qb + 16) {
      rm |= 1u << (ci - qb);
      bv = -1.f; bi = 1 << 30;
      #pragma unroll
      for (int j = 0; j < 16; ++j)
        if (!((rm >> j) & 1u) && lv[j] > bv) { bv = lv[j]; bi = qb + j; }
    }
  }
  __syncthreads();

  // 4-way merge of sorted lists (val desc, idx asc); quarters have disjoint,
  // increasing index ranges so the tournament's tie-break is globally exact.
  if (tid == 0) {
    int p0 = 0, p1 = 0, p2 = 0, p3 = 0;
    float v0 = wl_val[0][0], v1 = wl_val[1][0], v2 = wl_val[2][0], v3 = wl_val[3][0];
    int   i0 = wl_idx[0][0], i1 = wl_idx[1][0], i2 = wl_idx[2][0], i3 = wl_idx[3][0];
    for (int it = 0; it < KEFF; ++it) {
      float va = v0; int ia = i0; int sa = 0;
      if (v1 > va || (v1 == va && i1 < ia)) { va = v1; ia = i1; sa = 1; }
      if (v2 > va || (v2 == va && i2 < ia)) { va = v2; ia = i2; sa = 2; }
      if (v3 > va || (v3 == va && i3 < ia)) { va = v3; ia = i3; sa = 3; }
      topidx[b * KEFF + it]  = ia;
      topsal[b * KEFF + it]  = sal[ia];
      topcums[b * KEFF + it] = ya[ia];
      if      (sa == 0) { ++p0; v0 = (p0 < KEFF) ? wl_val[0][p0] : -1.f; i0 = (p0 < KEFF) ? wl_idx[0][p0] : (1 << 30); }
      else if (sa == 1) { ++p1; v1 = (p1 < KEFF) ? wl_val[1][p1] : -1.f; i1 = (p1 < KEFF) ? wl_idx[1][p1] : (1 << 30); }
      else if (sa == 2) { ++p2; v2 = (p2 < KEFF) ? wl_val[2][p2] : -1.f; i2 = (p2 < KEFF) ? wl_idx[2][p2] : (1 << 30); }
      else              { ++p3; v3 = (p3 < KEFF) ? wl_val[3][p3] : -1.f; i3 = (p3 < KEFF) ? wl_idx[3][p3] : (1 << 30); }
    }
  }
}

// ---------------------------------------------------------------------------
// Kernel 3: lift + L2-normalize + project for the 2048 selected anchors.
// (round-1 form: 256 blocks x 8 anchors, 256 threads)
// ---------------------------------------------------------------------------
__global__ __launch_bounds__(256) void k_tok(const float* __restrict__ x,
    const float* __restrict__ W_lift, const float* __restrict__ b_lift,
    const float* __restrict__ W_proj, const float* __restrict__ b_proj,
    const int* __restrict__ topidx, const float* __restrict__ topsal,
    const float* __restrict__ topcums, float* __restrict__ tokens)
{
  __shared__ float cloud[8][KL];
  const int tid = threadIdx.x;
  const int k = tid & 63;
  const int g = tid >> 6;
  const int b = blockIdx.x >> 3;
  const int nb = (blockIdx.x & 7) * 8;

  #pragma unroll
  for (int a = 0; a < 2; ++a) {
    int n = nb + g + a * 4;
    int t = topidx[b * KEFF + n];
    const float* xr = x + ((long)b * TT + t) * DD;
    float acc = 0.f;
    #pragma unroll 8
    for (int d4 = 0; d4 < DD / 4; ++d4) {
      float4 xv = *(const float4*)&xr[d4 * 4];
      acc = fmaf(xv.x, W_lift[(d4 * 4 + 0) * KL + k], acc);
      acc = fmaf(xv.y, W_lift[(d4 * 4 + 1) * KL + k], acc);
      acc = fmaf(xv.z, W_lift[(d4 * 4 + 2) * KL + k], acc);
      acc = fmaf(xv.w, W_lift[(d4 * 4 + 3) * KL + k], acc);
    }
    float s  = topsal[b * KEFF + n];
    float tp = (float)t / (float)TT;
    float cm = topcums[b * KEFF + n];
    acc = fmaf(s,  W_lift[128 * KL + k], acc);
    acc = fmaf(tp, W_lift[129 * KL + k], acc);
    acc = fmaf(cm, W_lift[130 * KL + k], acc);
    acc += b_lift[k];
    float ss = acc * acc;
    #pragma unroll
    for (int m = 1; m < 64; m <<= 1) ss += __shfl_xor(ss, m, 64);
    float denom = fmaxf(sqrtf(ss), 1e-6f);
    cloud[g + a * 4][k] = acc / denom;
  }
  __syncthreads();

  #pragma unroll
  for (int q = 0; q < 4; ++q) {
    int dcol = tid + q * 256;
    float accp[8];
    #pragma unroll
    for (int n = 0; n < 8; ++n) accp[n] = 0.f;
    for (int kk = 0; kk < KL; ++kk) {
      float w = W_proj[kk * DM + dcol];
      #pragma unroll
      for (int n = 0; n < 8; ++n) accp[n] = fmaf(cloud[n][kk], w, accp[n]);
    }
    float bp = b_proj[dcol];
    #pragma unroll
    for (int n = 0; n < 8; ++n)
      tokens[((long)b * KEFF + nb + n) * DM + dcol] = accp[n] + bp;
  }
}

extern "C" void kernel_launch(void* const* d_in, const int* in_sizes, int n_in,
                              void* d_out, int out_size, void* d_ws, size_t ws_size,
                              hipStream_t stream) {
  const float* x      = (const float*)d_in[0];
  const float* W1     = (const float*)d_in[1];
  const float* b1     = (const float*)d_in[2];
  // d_in[3] = w_e: event_scores are unused downstream -> skipped entirely
  const float* w_s    = (const float*)d_in[4];
  const float* W_lift = (const float*)d_in[5];
  const float* b_lift = (const float*)d_in[6];
  const float* W_proj = (const float*)d_in[7];
  const float* b_proj = (const float*)d_in[8];
  const float* logt   = (const float*)d_in[9];

  float* tokens = (float*)d_out;
  float* ysr    = tokens + (size_t)BB * KEFF * DM;   // y_star region (also
                                                     // scratch for saliency)
  int*   topidx  = (int*)d_ws;
  float* topsal  = (float*)((char*)d_ws + 8192);
  float* topcums = (float*)((char*)d_ws + 16384);

  k_sal<<<(BB * TT) / 64, 256, 0, stream>>>(x, W1, b1, w_s, ysr);
  k_sel<<<BB, 256, 0, stream>>>(logt, ysr, topidx, topsal, topcums);
  k_tok<<<BB * 8, 256, 0, stream>>>(x, W_lift, b_lift, W_proj, b_proj,
                                    topidx, topsal, topcums, tokens);
}

// Round 9
// 235.478 us; speedup vs baseline: 1.4802x; 1.4802x over previous
//
#include <hip/hip_runtime.h>
#include <math.h>

#define TT 4096
#define BB 32
#define DD 128
#define HH 256
#define KL 64
#define DM 1024
#define KEFF 64
#define KBUDGET 16.0f
#define LAM_ 0.5f

// fast tanh: 1 - 2/(1+exp2(x*2*log2e)); hw v_exp_f32 + v_rcp_f32 (~6 insts).
__device__ __forceinline__ float fast_tanh(float x) {
#if __has_builtin(__builtin_amdgcn_exp2f)
  float e = __builtin_amdgcn_exp2f(x * 2.885390081777927f);
#else
  float e = __expf(2.0f * x);
#endif
  float r = __builtin_amdgcn_rcpf(e + 1.0f);
  return fmaf(-2.0f, r, 1.0f);
}

// ---------------------------------------------------------------------------
// Kernel 1: saliency[b,t] = softplus( tanh(x@W1 + b1) @ w_s )
// 64 rows/block, 256 threads. x staged ONCE in LDS; W1 streamed from L2 with
// register double-buffer prefetch (wA/wB). launch_bounds(256,2): VGPR budget
// 256 so the ~180-reg demand (acc 64 + bufs 64 + xv 32 + addr) fits WITHOUT
// scratch spill (256,3 capped at ~170 -> compiler spilled bufs, r6: 375MB
// scratch writes, VALUBusy 32%).
// ---------------------------------------------------------------------------
__global__ __launch_bounds__(256, 2) void k_sal(const float* __restrict__ x,
    const float* __restrict__ W1, const float* __restrict__ b1,
    const float* __restrict__ w_s, float* __restrict__ sal_out)
{
  __shared__ float xs[64][132];     // 33792 B; row stride 132 -> rq rows hit
                                    // distinct bank quads on b128 reads
  __shared__ float redsm[4][64];

  const int tid  = threadIdx.x;
  const int lane = tid & 63;
  const int wave = tid >> 6;
  const int rq = lane & 7;          // row group: rows rq + 8i
  const int hq = lane >> 3;         // 0..7, 8 h each
  const int h0 = wave * 64 + hq * 8;
  const long rowbase = (long)blockIdx.x * 64;

  // stage x tile: 64 rows x 128 d (2048 float4, coalesced)
  #pragma unroll
  for (int p = 0; p < 8; ++p) {
    int i = tid + p * 256;
    int r = i >> 5, c4 = i & 31;
    float4 v = *(const float4*)&x[(rowbase + r) * DD + c4 * 4];
    *(float4*)&xs[r][c4 * 4] = v;
  }
  __syncthreads();

  float acc[8][8];
  #pragma unroll
  for (int i = 0; i < 8; ++i)
    #pragma unroll
    for (int j = 0; j < 8; ++j) acc[i][j] = 0.f;

  const float* __restrict__ Wb = W1 + h0;

#define LOADW(BUF, D4)                                        \
  {                                                           \
    const float* wp = Wb + (size_t)(D4) * 4 * HH;             \
    BUF[0] = *(const float4*)&wp[0];                          \
    BUF[1] = *(const float4*)&wp[4];                          \
    BUF[2] = *(const float4*)&wp[HH];                         \
    BUF[3] = *(const float4*)&wp[HH + 4];                     \
    BUF[4] = *(const float4*)&wp[2 * HH];                     \
    BUF[5] = *(const float4*)&wp[2 * HH + 4];                 \
    BUF[6] = *(const float4*)&wp[3 * HH];                     \
    BUF[7] = *(const float4*)&wp[3 * HH + 4];                 \
  }

#define FMAROW(I, XD, WA, WB)                      \
  acc[I][0] = fmaf(XD, WA.x, acc[I][0]);           \
  acc[I][1] = fmaf(XD, WA.y, acc[I][1]);           \
  acc[I][2] = fmaf(XD, WA.z, acc[I][2]);           \
  acc[I][3] = fmaf(XD, WA.w, acc[I][3]);           \
  acc[I][4] = fmaf(XD, WB.x, acc[I][4]);           \
  acc[I][5] = fmaf(XD, WB.y, acc[I][5]);           \
  acc[I][6] = fmaf(XD, WB.z, acc[I][6]);           \
  acc[I][7] = fmaf(XD, WB.w, acc[I][7]);
#define FMAD(C, WA, WB)                            \
  FMAROW(0, xv0.C, WA, WB)                         \
  FMAROW(1, xv1.C, WA, WB)                         \
  FMAROW(2, xv2.C, WA, WB)                         \
  FMAROW(3, xv3.C, WA, WB)                         \
  FMAROW(4, xv4.C, WA, WB)                         \
  FMAROW(5, xv5.C, WA, WB)                         \
  FMAROW(6, xv6.C, WA, WB)                         \
  FMAROW(7, xv7.C, WA, WB)

#define FMABLOCK(D4, W)                                       \
  {                                                           \
    float4 xv0 = *(const float4*)&xs[rq +  0][(D4) * 4];      \
    float4 xv1 = *(const float4*)&xs[rq +  8][(D4) * 4];      \
    float4 xv2 = *(const float4*)&xs[rq + 16][(D4) * 4];      \
    float4 xv3 = *(const float4*)&xs[rq + 24][(D4) * 4];      \
    float4 xv4 = *(const float4*)&xs[rq + 32][(D4) * 4];      \
    float4 xv5 = *(const float4*)&xs[rq + 40][(D4) * 4];      \
    float4 xv6 = *(const float4*)&xs[rq + 48][(D4) * 4];      \
    float4 xv7 = *(const float4*)&xs[rq + 56][(D4) * 4];      \
    FMAD(x, W[0], W[1])                                       \
    FMAD(y, W[2], W[3])                                       \
    FMAD(z, W[4], W[5])                                       \
    FMAD(w, W[6], W[7])                                       \
  }

  float4 wA[8], wB[8];
  LOADW(wA, 0)
  #pragma unroll 1
  for (int d4 = 0; d4 < 30; d4 += 2) {
    LOADW(wB, d4 + 1)      // in flight while wA is consumed
    FMABLOCK(d4, wA)
    LOADW(wA, d4 + 2)      // in flight while wB is consumed
    FMABLOCK(d4 + 1, wB)
  }
  LOADW(wB, 31)
  FMABLOCK(30, wA)
  FMABLOCK(31, wB)

#undef FMABLOCK
#undef FMAD
#undef FMAROW
#undef LOADW

  // epilogue: tanh + w_s dot over this lane's 8 h columns
  float4 ba  = *(const float4*)&b1[h0];
  float4 bb  = *(const float4*)&b1[h0 + 4];
  float4 wsa = *(const float4*)&w_s[h0];
  float4 wsb = *(const float4*)&w_s[h0 + 4];
  float s_acc[8];
  #pragma unroll
  for (int i = 0; i < 8; ++i) {
    float s = 0.f;
    s = fmaf(fast_tanh(acc[i][0] + ba.x), wsa.x, s);
    s = fmaf(fast_tanh(acc[i][1] + ba.y), wsa.y, s);
    s = fmaf(fast_tanh(acc[i][2] + ba.z), wsa.z, s);
    s = fmaf(fast_tanh(acc[i][3] + ba.w), wsa.w, s);
    s = fmaf(fast_tanh(acc[i][4] + bb.x), wsb.x, s);
    s = fmaf(fast_tanh(acc[i][5] + bb.y), wsb.y, s);
    s = fmaf(fast_tanh(acc[i][6] + bb.z), wsb.z, s);
    s = fmaf(fast_tanh(acc[i][7] + bb.w), wsb.w, s);
    s_acc[i] = s;
  }
  // reduce across the 8 hq groups (masks 8,16,32)
  #pragma unroll
  for (int m = 8; m < 64; m <<= 1) {
    #pragma unroll
    for (int i = 0; i < 8; ++i) s_acc[i] += __shfl_xor(s_acc[i], m, 64);
  }
  if (hq == 0) {
    #pragma unroll
    for (int i = 0; i < 8; ++i) redsm[wave][rq + 8 * i] = s_acc[i];
  }
  __syncthreads();
  if (tid < 64) {
    float z = redsm[0][tid] + redsm[1][tid] + redsm[2][tid] + redsm[3][tid];
    float sp = fmaxf(z, 0.f) + log1pf(expf(-fabsf(z)));  // stable softplus
    sal_out[rowbase + tid] = sp;
  }
}

// ---------------------------------------------------------------------------
// Kernel 2: per-batch selector. y_star + cumsum + exact top-64
// (desc value, ties -> lower index). Top-64: each wave builds the exact
// sorted top-64 of its 1024-quarter (registers + bitmask, shuffle-only, NO
// barriers), then one thread 4-way-merges the sorted lists (64 steps).
// ---------------------------------------------------------------------------
__global__ __launch_bounds__(256) void k_sel(const float* __restrict__ logt,
    float* __restrict__ ysr, int* __restrict__ topidx,
    float* __restrict__ topsal, float* __restrict__ topcums)
{
  __shared__ float sal[TT];
  __shared__ float ya[TT];   // y (pre-refractory), then reused as cumsum
  __shared__ float yb[TT];   // y_star
  __shared__ float redf[8];
  __shared__ float wl_val[4][KEFF];
  __shared__ int   wl_idx[4][KEFF];

  const int tid = threadIdx.x;
  const int lane = tid & 63;
  const int wave = tid >> 6;
  const int b = blockIdx.x;
  float* row = ysr + (long)b * TT;

  for (int i = tid; i < TT; i += 256) sal[i] = row[i];
  __syncthreads();

  float temp = expf(logt[0]);
  temp = fminf(fmaxf(temp, 0.1f), 10.f);
  const float inv2lam = 1.0f / (2.0f * LAM_);

  for (int i = tid; i < TT; i += 256) {
    float z = (sal[i] * inv2lam - 0.5f) / temp;
    float s;
    if (z >= 0.f) { float e = expf(-z); s = 1.f / (1.f + e); }
    else          { float e = expf(z);  s = e / (1.f + e); }
    ya[i] = (i == 0) ? 0.f : s;
  }
  __syncthreads();

  float loc = 0.f;
  for (int i = tid; i < TT; i += 256) loc += ya[i];
  #pragma unroll
  for (int m = 1; m < 64; m <<= 1) loc += __shfl_xor(loc, m, 64);
  if (lane == 0) redf[wave] = loc;
  __syncthreads();
  float budget = redf[0] + redf[1] + redf[2] + redf[3];
  float scale = fminf(KBUDGET / fmaxf(budget, 1e-6f), 1.f);

  for (int i = tid; i < TT; i += 256) {
    float yi = ya[i] * scale;
    float yj = ya[(i + 1) & (TT - 1)] * scale;
    float m = fminf(2.f / (1.f + (yi + yj)), 1.f);
    yb[i] = (i == 0) ? 0.f : yi * m;
  }
  __syncthreads();

  for (int i = tid; i < TT; i += 256) row[i] = yb[i];   // y_star out

  // inclusive cumsum of saliency into ya
  const int base = tid * 16;
  float run = 0.f;
  #pragma unroll
  for (int j = 0; j < 16; ++j) { run += sal[base + j]; ya[base + j] = run; }
  float v = run;
  #pragma unroll
  for (int m = 1; m < 64; m <<= 1) {
    float u = __shfl_up(v, (unsigned)m, 64);
    if (lane >= m) v += u;
  }
  float lexcl = v - run;
  if (lane == 63) redf[4 + wave] = v;
  __syncthreads();
  float woff = 0.f;
  for (int w = 0; w < wave; ++w) woff += redf[4 + w];
  float off = woff + lexcl;
  #pragma unroll
  for (int j = 0; j < 16; ++j) ya[base + j] += off;
  __syncthreads();

  // per-wave exact sorted top-64 of its quarter (no barriers)
  const int qb = wave * 1024 + lane * 16;
  float lv[16];
  #pragma unroll
  for (int j = 0; j < 16; ++j) lv[j] = yb[qb + j];
  unsigned rm = 0;
  float bv = -1.f; int bi = 1 << 30;
  #pragma unroll
  for (int j = 0; j < 16; ++j)
    if (lv[j] > bv) { bv = lv[j]; bi = qb + j; }

  for (int it = 0; it < KEFF; ++it) {
    float cv = bv; int ci = bi;
    #pragma unroll
    for (int m = 1; m < 64; m <<= 1) {
      float ov = __shfl_xor(cv, m, 64);
      int   oi = __shfl_xor(ci, m, 64);
      if (ov > cv || (ov == cv && oi < ci)) { cv = ov; ci = oi; }
    }
    if (lane == 0) { wl_val[wave][it] = cv; wl_idx[wave][it] = ci; }
    if (ci >= qb && ci < qb + 16) {
      rm |= 1u << (ci - qb);
      bv = -1.f; bi = 1 << 30;
      #pragma unroll
      for (int j = 0; j < 16; ++j)
        if (!((rm >> j) & 1u) && lv[j] > bv) { bv = lv[j]; bi = qb + j; }
    }
  }
  __syncthreads();

  // 4-way merge of sorted lists (val desc, idx asc); quarters have disjoint,
  // increasing index ranges so the tournament's tie-break is globally exact.
  if (tid == 0) {
    int p0 = 0, p1 = 0, p2 = 0, p3 = 0;
    float v0 = wl_val[0][0], v1 = wl_val[1][0], v2 = wl_val[2][0], v3 = wl_val[3][0];
    int   i0 = wl_idx[0][0], i1 = wl_idx[1][0], i2 = wl_idx[2][0], i3 = wl_idx[3][0];
    for (int it = 0; it < KEFF; ++it) {
      float va = v0; int ia = i0; int sa = 0;
      if (v1 > va || (v1 == va && i1 < ia)) { va = v1; ia = i1; sa = 1; }
      if (v2 > va || (v2 == va && i2 < ia)) { va = v2; ia = i2; sa = 2; }
      if (v3 > va || (v3 == va && i3 < ia)) { va = v3; ia = i3; sa = 3; }
      topidx[b * KEFF + it]  = ia;
      topsal[b * KEFF + it]  = sal[ia];
      topcums[b * KEFF + it] = ya[ia];
      if      (sa == 0) { ++p0; v0 = (p0 < KEFF) ? wl_val[0][p0] : -1.f; i0 = (p0 < KEFF) ? wl_idx[0][p0] : (1 << 30); }
      else if (sa == 1) { ++p1; v1 = (p1 < KEFF) ? wl_val[1][p1] : -1.f; i1 = (p1 < KEFF) ? wl_idx[1][p1] : (1 << 30); }
      else if (sa == 2) { ++p2; v2 = (p2 < KEFF) ? wl_val[2][p2] : -1.f; i2 = (p2 < KEFF) ? wl_idx[2][p2] : (1 << 30); }
      else              { ++p3; v3 = (p3 < KEFF) ? wl_val[3][p3] : -1.f; i3 = (p3 < KEFF) ? wl_idx[3][p3] : (1 << 30); }
    }
  }
}

// ---------------------------------------------------------------------------
// Kernel 3: lift + L2-normalize + project for the 2048 selected anchors.
// (round-1 form: 256 blocks x 8 anchors, 256 threads)
// ---------------------------------------------------------------------------
__global__ __launch_bounds__(256) void k_tok(const float* __restrict__ x,
    const float* __restrict__ W_lift, const float* __restrict__ b_lift,
    const float* __restrict__ W_proj, const float* __restrict__ b_proj,
    const int* __restrict__ topidx, const float* __restrict__ topsal,
    const float* __restrict__ topcums, float* __restrict__ tokens)
{
  __shared__ float cloud[8][KL];
  const int tid = threadIdx.x;
  const int k = tid & 63;
  const int g = tid >> 6;
  const int b = blockIdx.x >> 3;
  const int nb = (blockIdx.x & 7) * 8;

  #pragma unroll
  for (int a = 0; a < 2; ++a) {
    int n = nb + g + a * 4;
    int t = topidx[b * KEFF + n];
    const float* xr = x + ((long)b * TT + t) * DD;
    float acc = 0.f;
    #pragma unroll 8
    for (int d4 = 0; d4 < DD / 4; ++d4) {
      float4 xv = *(const float4*)&xr[d4 * 4];
      acc = fmaf(xv.x, W_lift[(d4 * 4 + 0) * KL + k], acc);
      acc = fmaf(xv.y, W_lift[(d4 * 4 + 1) * KL + k], acc);
      acc = fmaf(xv.z, W_lift[(d4 * 4 + 2) * KL + k], acc);
      acc = fmaf(xv.w, W_lift[(d4 * 4 + 3) * KL + k], acc);
    }
    float s  = topsal[b * KEFF + n];
    float tp = (float)t / (float)TT;
    float cm = topcums[b * KEFF + n];
    acc = fmaf(s,  W_lift[128 * KL + k], acc);
    acc = fmaf(tp, W_lift[129 * KL + k], acc);
    acc = fmaf(cm, W_lift[130 * KL + k], acc);
    acc += b_lift[k];
    float ss = acc * acc;
    #pragma unroll
    for (int m = 1; m < 64; m <<= 1) ss += __shfl_xor(ss, m, 64);
    float denom = fmaxf(sqrtf(ss), 1e-6f);
    cloud[g + a * 4][k] = acc / denom;
  }
  __syncthreads();

  #pragma unroll
  for (int q = 0; q < 4; ++q) {
    int dcol = tid + q * 256;
    float accp[8];
    #pragma unroll
    for (int n = 0; n < 8; ++n) accp[n] = 0.f;
    for (int kk = 0; kk < KL; ++kk) {
      float w = W_proj[kk * DM + dcol];
      #pragma unroll
      for (int n = 0; n < 8; ++n) accp[n] = fmaf(cloud[n][kk], w, accp[n]);
    }
    float bp = b_proj[dcol];
    #pragma unroll
    for (int n = 0; n < 8; ++n)
      tokens[((long)b * KEFF + nb + n) * DM + dcol] = accp[n] + bp;
  }
}

extern "C" void kernel_launch(void* const* d_in, const int* in_sizes, int n_in,
                              void* d_out, int out_size, void* d_ws, size_t ws_size,
                              hipStream_t stream) {
  const float* x      = (const float*)d_in[0];
  const float* W1     = (const float*)d_in[1];
  const float* b1     = (const float*)d_in[2];
  // d_in[3] = w_e: event_scores are unused downstream -> skipped entirely
  const float* w_s    = (const float*)d_in[4];
  const float* W_lift = (const float*)d_in[5];
  const float* b_lift = (const float*)d_in[6];
  const float* W_proj = (const float*)d_in[7];
  const float* b_proj = (const float*)d_in[8];
  const float* logt   = (const float*)d_in[9];

  float* tokens = (float*)d_out;
  float* ysr    = tokens + (size_t)BB * KEFF * DM;   // y_star region (also
                                                     // scratch for saliency)
  int*   topidx  = (int*)d_ws;
  float* topsal  = (float*)((char*)d_ws + 8192);
  float* topcums = (float*)((char*)d_ws + 16384);

  k_sal<<<(BB * TT) / 64, 256, 0, stream>>>(x, W1, b1, w_s, ysr);
  k_sel<<<BB, 256, 0, stream>>>(logt, ysr, topidx, topsal, topcums);
  k_tok<<<BB * 8, 256, 0, stream>>>(x, W_lift, b_lift, W_proj, b_proj,
                                    topidx, topsal, topcums, tokens);
}